// Round 7
// baseline (154.734 us; speedup 1.0000x reference)
//
#include <hip/hip_runtime.h>
#include <math.h>

#define B 4
#define DEC 256
#define ENC 256
#define HDIM 512

// exp2(x*TANH_SCALE) == e^{2x};  tanh(x) = 1 - 2/(1+e^{2x})
#define TANH_SCALE 2.8853900817779268f
#define LOG2E 1.4426950408889634f

__device__ __forceinline__ float fast_exp2(float x) { return __builtin_amdgcn_exp2f(x); }
__device__ __forceinline__ float fast_rcp(float x)  { return __builtin_amdgcn_rcpf(x); }

// ---------------------------------------------------------------------------
// proj v5: 16 rows x 128-m stripe per block, 256 thr, full K per thread.
//   tx = tid & 31  -> m-quad within stripe (m0 = stripe*128 + tx*4)
//   ty = tid >> 5  -> row-pair (2 rows each; lanes 0-31/32-63 differ -> no
//                     scalarization; X loads are 2-line vector broadcasts)
// W loads: 32 lanes x 16 B = 512 B contiguous/instr (lane-dup across half-waves).
// Double-buffered 8-k chunks. No k-split -> no LDS, no barriers.
// grid (64, 4, 2): 64 row-groups x 4 m-stripes x {enc,dec} = 512 blocks (2/CU).
//  z=0: E^T[b][m][e] = exp2(TANH_SCALE * enc@W_mlp[:H])
//  z=1: D[b*DEC+d][m] = exp2(TANH_SCALE * (dec@W_mlp[H:] + b_mlp))
// ---------------------------------------------------------------------------
#define P5_LOAD(WB, XB, KOFF)                                               \
    _Pragma("unroll")                                                       \
    for (int kk = 0; kk < 8; ++kk)                                          \
        WB[kk] = *(const float4*)&Wp[(long)((KOFF) + kk) * 512];            \
    XB[0] = *(const float4*)&x0[(KOFF)];                                    \
    XB[1] = *(const float4*)&x0[(KOFF) + 4];                                \
    XB[2] = *(const float4*)&x1[(KOFF)];                                    \
    XB[3] = *(const float4*)&x1[(KOFF) + 4];

#define P5_FMA(WB, XB)                                                      \
    _Pragma("unroll")                                                       \
    for (int kk = 0; kk < 8; ++kk) {                                        \
        float4 w = WB[kk];                                                  \
        float xv0 = ((const float*)&XB[kk >> 2])[kk & 3];                   \
        float xv1 = ((const float*)&XB[2 + (kk >> 2)])[kk & 3];             \
        acc[0][0] = fmaf(xv0, w.x, acc[0][0]);                              \
        acc[0][1] = fmaf(xv0, w.y, acc[0][1]);                              \
        acc[0][2] = fmaf(xv0, w.z, acc[0][2]);                              \
        acc[0][3] = fmaf(xv0, w.w, acc[0][3]);                              \
        acc[1][0] = fmaf(xv1, w.x, acc[1][0]);                              \
        acc[1][1] = fmaf(xv1, w.y, acc[1][1]);                              \
        acc[1][2] = fmaf(xv1, w.z, acc[1][2]);                              \
        acc[1][3] = fmaf(xv1, w.w, acc[1][3]);                              \
    }

__global__ __launch_bounds__(256) void proj_kernel(
    const float* __restrict__ enc, const float* __restrict__ dec,
    const float* __restrict__ Wmlp, const float* __restrict__ bmlp,
    float* __restrict__ ET, float* __restrict__ Dmat)
{
    const int tid = threadIdx.x;
    const int tx = tid & 31, ty = tid >> 5;
    const int m0 = blockIdx.y * 128 + tx * 4;
    const int r0 = blockIdx.x * 16 + ty * 2;          // global row (2 rows)
    const bool encside = (blockIdx.z == 0);
    const float* X = encside ? enc : dec;
    const float* Wp = (encside ? Wmlp : Wmlp + HDIM * HDIM) + m0;
    const float* x0 = X + (long)r0 * HDIM;
    const float* x1 = x0 + HDIM;

    float acc[2][4] = {};
    float4 Wa[8], Wb[8], Xa[4], Xb[4];

    P5_LOAD(Wa, Xa, 0)
    for (int k0 = 0; k0 < HDIM; k0 += 16) {
        P5_LOAD(Wb, Xb, k0 + 8)
        P5_FMA(Wa, Xa)
        if (k0 + 16 < HDIM) { P5_LOAD(Wa, Xa, k0 + 16) }
        P5_FMA(Wb, Xb)
    }

    if (encside) {
        const int batch = r0 >> 8, e0 = r0 & 255;
        float* outb = ET + (long)batch * HDIM * ENC + e0;
#pragma unroll
        for (int j = 0; j < 4; ++j) {
            outb[(long)(m0 + j) * ENC]     = fast_exp2(acc[0][j] * TANH_SCALE);
            outb[(long)(m0 + j) * ENC + 1] = fast_exp2(acc[1][j] * TANH_SCALE);
        }
    } else {
        const float4 bq = *(const float4*)&bmlp[m0];
        float* outb = Dmat + (long)r0 * HDIM + m0;
        float4 v0, v1;
        v0.x = fast_exp2((acc[0][0] + bq.x) * TANH_SCALE);
        v0.y = fast_exp2((acc[0][1] + bq.y) * TANH_SCALE);
        v0.z = fast_exp2((acc[0][2] + bq.z) * TANH_SCALE);
        v0.w = fast_exp2((acc[0][3] + bq.w) * TANH_SCALE);
        v1.x = fast_exp2((acc[1][0] + bq.x) * TANH_SCALE);
        v1.y = fast_exp2((acc[1][1] + bq.y) * TANH_SCALE);
        v1.z = fast_exp2((acc[1][2] + bq.z) * TANH_SCALE);
        v1.w = fast_exp2((acc[1][3] + bq.w) * TANH_SCALE);
        *(float4*)&outb[0] = v0;
        *(float4*)&outb[HDIM] = v1;
    }
}

// ---------------------------------------------------------------------------
// attn v3: thread = e (256/block), 2 d-rows/block, 512 blocks (2/CU).
// D0/D1/wo staged in LDS once, read via same-address ds_read_b128 broadcast
// (conflict-free) -> NO scalar loads in the hot loop. E^T coalesced with
// 16-deep register prefetch. logit = -2 * sum_m wo*rcp(fma(E,D,1)).
// ---------------------------------------------------------------------------
__global__ __launch_bounds__(256) void attn_kernel(
    const float* __restrict__ Dmat, const float* __restrict__ ET,
    const float* __restrict__ wo,
    const float* __restrict__ enc, const unsigned char* __restrict__ extm,
    float* __restrict__ attn_out)
{
    __shared__ __align__(16) float d0s[HDIM];
    __shared__ __align__(16) float d1s[HDIM];
    __shared__ __align__(16) float wos[HDIM];
    __shared__ float red[2][4][2];

    const int tid = threadIdx.x, lane = tid & 63, wave = tid >> 6;
    const int b = blockIdx.y, d0 = blockIdx.x * 2;

    const float* D0 = Dmat + ((long)b * DEC + d0) * HDIM;
    const float* ecol = ET + (long)b * HDIM * ENC + tid;

    // stage D0, D1, wo (coalesced float2 per thread)
    *(float2*)&d0s[tid * 2] = *(const float2*)&D0[tid * 2];
    *(float2*)&d1s[tid * 2] = *(const float2*)&D0[HDIM + tid * 2];
    *(float2*)&wos[tid * 2] = *(const float2*)&wo[tid * 2];

    float ev[16], nv[16];
#pragma unroll
    for (int j = 0; j < 16; ++j) ev[j] = ecol[j * ENC];
    __syncthreads();

    float acc0 = 0.f, acc1 = 0.f;
    for (int m = 0; m < HDIM; m += 16) {
        if (m + 16 < HDIM) {
#pragma unroll
            for (int j = 0; j < 16; ++j) nv[j] = ecol[(m + 16 + j) * ENC];
        }
        float4 dv0[4], dv1[4], wv[4];
#pragma unroll
        for (int q = 0; q < 4; ++q) {
            dv0[q] = *(const float4*)&d0s[m + q * 4];   // ds_read_b128 broadcast
            dv1[q] = *(const float4*)&d1s[m + q * 4];
            wv[q]  = *(const float4*)&wos[m + q * 4];
        }
#pragma unroll
        for (int j = 0; j < 16; ++j) {
            float w  = ((const float*)&wv[j >> 2])[j & 3];
            float t0 = fmaf(ev[j], ((const float*)&dv0[j >> 2])[j & 3], 1.0f);
            float t1 = fmaf(ev[j], ((const float*)&dv1[j >> 2])[j & 3], 1.0f);
            acc0 = fmaf(w, fast_rcp(t0), acc0);
            acc1 = fmaf(w, fast_rcp(t1), acc1);
        }
#pragma unroll
        for (int j = 0; j < 16; ++j) ev[j] = nv[j];
    }

    // masks + effective logits (softmax-invariant constants dropped)
    const int e = tid;
    const bool pad = (enc[((long)b * ENC + e) * HDIM] == 0.0f);
    const bool x0m = extm[((long)(b * DEC) + d0) * ENC + e] != 0;
    const bool x1m = extm[((long)(b * DEC) + d0 + 1) * ENC + e] != 0;
    float l0 = (pad || x0m) ? -__builtin_inff() : -2.0f * acc0;
    float l1 = (pad || x1m) ? -__builtin_inff() : -2.0f * acc1;

    // softmax over e (4 waves)
    float m0 = l0, m1 = l1;
#pragma unroll
    for (int off = 32; off >= 1; off >>= 1) {
        m0 = fmaxf(m0, __shfl_xor(m0, off, 64));
        m1 = fmaxf(m1, __shfl_xor(m1, off, 64));
    }
    if (lane == 0) { red[0][wave][0] = m0; red[0][wave][1] = m1; }
    __syncthreads();
    const float gm0 = fmaxf(fmaxf(red[0][0][0], red[0][1][0]), fmaxf(red[0][2][0], red[0][3][0]));
    const float gm1 = fmaxf(fmaxf(red[0][0][1], red[0][1][1]), fmaxf(red[0][2][1], red[0][3][1]));
    float p0 = fast_exp2((l0 - gm0) * LOG2E);
    float p1 = fast_exp2((l1 - gm1) * LOG2E);
    float s0 = p0, s1 = p1;
#pragma unroll
    for (int off = 32; off >= 1; off >>= 1) {
        s0 += __shfl_xor(s0, off, 64);
        s1 += __shfl_xor(s1, off, 64);
    }
    if (lane == 0) { red[1][wave][0] = s0; red[1][wave][1] = s1; }
    __syncthreads();
    const float gs0 = red[1][0][0] + red[1][1][0] + red[1][2][0] + red[1][3][0];
    const float gs1 = red[1][0][1] + red[1][1][1] + red[1][2][1] + red[1][3][1];
    attn_out[((long)(b * DEC) + d0) * ENC + e] = p0 * fast_rcp(gs0);
    attn_out[((long)(b * DEC) + d0 + 1) * ENC + e] = p1 * fast_rcp(gs1);
}

// ---------------------------------------------------------------------------
// ctx v3: 8 d-rows x 256-h stripe per block, 256 thr.
//   tx = tid & 63 -> h-quad; ty = tid >> 6 -> 2 d-rows.
// attn rows staged in LDS (8 KB = 2048 floats; 2 x float4 per thread covers
// ALL of it — the round-6 bug staged only half), read via ds_read_b128
// broadcast. enc streamed coalesced (1 KB/instr), double-buffered.
// grid (128, 2): rows span b*DEC+d (blocks never straddle b). 256 blocks.
// ---------------------------------------------------------------------------
#define C5_LOADW(WB, KOFF)                                                  \
    _Pragma("unroll")                                                       \
    for (int kk = 0; kk < 8; ++kk)                                          \
        WB[kk] = *(const float4*)&We[(long)((KOFF) + kk) * HDIM];

#define C5_FMA(WB, KOFF)                                                    \
    _Pragma("unroll")                                                       \
    for (int q = 0; q < 2; ++q) {                                           \
        float4 xq0 = *(const float4*)&as8[r0l][(KOFF) + q * 4];             \
        float4 xq1 = *(const float4*)&as8[r0l + 1][(KOFF) + q * 4];         \
        _Pragma("unroll")                                                   \
        for (int kk = 0; kk < 4; ++kk) {                                    \
            float4 w = WB[q * 4 + kk];                                      \
            float xv0 = ((const float*)&xq0)[kk];                           \
            float xv1 = ((const float*)&xq1)[kk];                           \
            acc[0][0] = fmaf(xv0, w.x, acc[0][0]);                          \
            acc[0][1] = fmaf(xv0, w.y, acc[0][1]);                          \
            acc[0][2] = fmaf(xv0, w.z, acc[0][2]);                          \
            acc[0][3] = fmaf(xv0, w.w, acc[0][3]);                          \
            acc[1][0] = fmaf(xv1, w.x, acc[1][0]);                          \
            acc[1][1] = fmaf(xv1, w.y, acc[1][1]);                          \
            acc[1][2] = fmaf(xv1, w.z, acc[1][2]);                          \
            acc[1][3] = fmaf(xv1, w.w, acc[1][3]);                          \
        }                                                                   \
    }

__global__ __launch_bounds__(256) void context_kernel(
    const float* __restrict__ attn, const float* __restrict__ enc,
    float* __restrict__ ctx)
{
    __shared__ __align__(16) float as8[8][ENC];
    const int tid = threadIdx.x;
    const int tx = tid & 63, ty = tid >> 6;
    const int r0 = blockIdx.x * 8;                 // 8 global rows (b*DEC+d)
    const int b = r0 >> 8;
    const int h0 = blockIdx.y * 256 + tx * 4;
    const int r0l = ty * 2;                        // this thread's 2 local rows
    const float* We = enc + (long)b * ENC * HDIM + h0;

    // stage 8 attn rows = 2048 floats: 2 x float4 per thread (full coverage)
    {
        const float* ag = attn + (long)r0 * ENC;
#pragma unroll
        for (int i = 0; i < 2; ++i) {
            int idx = (tid + i * 256) * 4;         // 512 float4s = 2048 floats
            *(float4*)&as8[0][idx] = *(const float4*)&ag[idx];
        }
    }

    float acc[2][4] = {};
    float4 Wa[8], Wb[8];
    C5_LOADW(Wa, 0)
    __syncthreads();

    for (int k0 = 0; k0 < ENC; k0 += 16) {
        C5_LOADW(Wb, k0 + 8)
        C5_FMA(Wa, k0)
        if (k0 + 16 < ENC) { C5_LOADW(Wa, k0 + 16) }
        C5_FMA(Wb, k0 + 8)
    }

#pragma unroll
    for (int i = 0; i < 2; ++i)
        *(float4*)&ctx[(long)(r0 + r0l + i) * HDIM + h0] =
            make_float4(acc[i][0], acc[i][1], acc[i][2], acc[i][3]);
}

// ---------------------------------------------------------------------------
extern "C" void kernel_launch(void* const* d_in, const int* in_sizes, int n_in,
                              void* d_out, int out_size, void* d_ws, size_t ws_size,
                              hipStream_t stream) {
    const float* dec = (const float*)d_in[0];
    const float* enc = (const float*)d_in[1];
    const unsigned char* extm = (const unsigned char*)d_in[2];
    const float* Wmlp = (const float*)d_in[3];
    const float* bmlp = (const float*)d_in[4];
    const float* Wout = (const float*)d_in[5];
    // d_in[6] = b_out: additive constant, cancels in softmax

    float* ctx = (float*)d_out;                    // [B, DEC, H]
    float* attn = ctx + (size_t)B * DEC * HDIM;    // [B, DEC, ENC]

    float* ET = (float*)d_ws;                      // [B][H][ENC] exp2(scaled enc-proj)^T
    float* Dmat = ET + (size_t)B * HDIM * ENC;     // [B*DEC][H] exp2(scaled dec-proj + bias)

    proj_kernel<<<dim3(64, 4, 2), 256, 0, stream>>>(enc, dec, Wmlp, bmlp, ET, Dmat);
    attn_kernel<<<dim3(DEC / 2, B), 256, 0, stream>>>(Dmat, ET, Wout, enc, extm, attn);
    context_kernel<<<dim3(128, 2), 256, 0, stream>>>(attn, enc, ctx);
}

// Round 8
// 138.587 us; speedup vs baseline: 1.1165x; 1.1165x over previous
//
#include <hip/hip_runtime.h>
#include <math.h>

#define B 4
#define DEC 256
#define ENC 256
#define HDIM 512

// exp2(x*TANH_SCALE) == e^{2x};  tanh(x) = 1 - 2/(1+e^{2x})
#define TANH_SCALE 2.8853900817779268f
#define LOG2E 1.4426950408889634f

__device__ __forceinline__ float fast_exp2(float x) { return __builtin_amdgcn_exp2f(x); }
__device__ __forceinline__ float fast_rcp(float x)  { return __builtin_amdgcn_rcpf(x); }

typedef __attribute__((ext_vector_type(8))) short bf16x8;   // 8 bf16 = 4 VGPR
typedef __attribute__((ext_vector_type(4))) short bf16x4;
typedef __attribute__((ext_vector_type(4))) float f32x4;

__device__ __forceinline__ unsigned short bf16_rne(float x) {
    unsigned u = __float_as_uint(x);
    return (unsigned short)((u + 0x7FFFu + ((u >> 16) & 1u)) >> 16);
}
__device__ __forceinline__ float bf16_to_f(unsigned short h) {
    return __uint_as_float((unsigned)h << 16);
}

// ---------------------------------------------------------------------------
// convert: fp32 -> bf16 hi/lo split.
//  z=0/1: X (enc/dec) [1024][512] -> Xh/Xl same layout. 8 els/thread.
//  z=2/3: W half (enc/dec) [512k][512m] -> WhT/WlT TRANSPOSED [512m][512k]
//         (so MFMA B-frags read 8 contiguous k). 4 els/thread, coalesced reads.
// grid (256, 1, 4) x 256 thr.
// ---------------------------------------------------------------------------
__global__ __launch_bounds__(256) void convert_kernel(
    const float* __restrict__ enc, const float* __restrict__ dec,
    const float* __restrict__ Wmlp,
    unsigned short* __restrict__ Xh_e, unsigned short* __restrict__ Xl_e,
    unsigned short* __restrict__ Xh_d, unsigned short* __restrict__ Xl_d,
    unsigned short* __restrict__ Wh_e, unsigned short* __restrict__ Wl_e,
    unsigned short* __restrict__ Wh_d, unsigned short* __restrict__ Wl_d)
{
    const int tid = threadIdx.x, z = blockIdx.z;
    if (z < 2) {
        const float* X = z ? dec : enc;
        unsigned short* H = z ? Xh_d : Xh_e;
        unsigned short* L = z ? Xl_d : Xl_e;
        const long i8 = ((long)blockIdx.x * 256 + tid) * 8;
        float4 v0 = *(const float4*)(X + i8);
        float4 v1 = *(const float4*)(X + i8 + 4);
        float xs[8] = {v0.x, v0.y, v0.z, v0.w, v1.x, v1.y, v1.z, v1.w};
        bf16x8 hv, lv;
#pragma unroll
        for (int j = 0; j < 8; ++j) {
            unsigned short h = bf16_rne(xs[j]);
            hv[j] = (short)h;
            lv[j] = (short)bf16_rne(xs[j] - bf16_to_f(h));
        }
        *(bf16x8*)(H + i8) = hv;
        *(bf16x8*)(L + i8) = lv;
    } else {
        const float* Wsrc = Wmlp + (z == 3 ? (long)HDIM * HDIM : 0);
        unsigned short* H = (z == 3) ? Wh_d : Wh_e;
        unsigned short* L = (z == 3) ? Wl_d : Wl_e;
        const int t = blockIdx.x * 256 + tid;     // 0..65535
        const int m = t & 511;
        const int k0 = (t >> 9) << 2;             // 0..508
        bf16x4 hv, lv;
#pragma unroll
        for (int j = 0; j < 4; ++j) {
            float x = Wsrc[(long)(k0 + j) * 512 + m];   // coalesced across lanes
            unsigned short h = bf16_rne(x);
            hv[j] = (short)h;
            lv[j] = (short)bf16_rne(x - bf16_to_f(h));
        }
        *(bf16x4*)(H + (long)m * 512 + k0) = hv;
        *(bf16x4*)(L + (long)m * 512 + k0) = lv;
    }
}

// ---------------------------------------------------------------------------
// proj via MFMA (bf16 hi/lo split, 3 mfma per K-step: hh + hl + lh).
// Block = 4 waves; wave computes one 16x16 C-tile; block = 64 rows x 16 m.
// Frag layouts (mfma_f32_16x16x32_bf16):
//   A[m = lane&15][k = (lane>>4)*8 + j]   (Xh/Xl k-major -> 16 B load)
//   B[k = (lane>>4)*8 + j][n = lane&15]   (WhT/WlT k-major -> 16 B load)
//   C/D: col = lane&15, row = (lane>>4)*4 + reg
// K-loop 512/32 = 16 iters, register double-buffer, two acc chains.
// grid (16, 32, 2) = 1024 blocks -> 4 blocks/CU, 16 waves/CU.
//  z=0: ET[b][m][e] = exp2(TS * enc@W[:H])   (transposed store, float4/lane)
//  z=1: Dmat[r][m]  = exp2(TS * (dec@W[H:] + b_mlp))
// ---------------------------------------------------------------------------
__global__ __launch_bounds__(256) void proj_mfma_kernel(
    const unsigned short* __restrict__ Xh_e, const unsigned short* __restrict__ Xl_e,
    const unsigned short* __restrict__ Xh_d, const unsigned short* __restrict__ Xl_d,
    const unsigned short* __restrict__ Wh_e, const unsigned short* __restrict__ Wl_e,
    const unsigned short* __restrict__ Wh_d, const unsigned short* __restrict__ Wl_d,
    const float* __restrict__ bmlp,
    float* __restrict__ ET, float* __restrict__ Dmat)
{
    const int tid = threadIdx.x;
    const int wave = tid >> 6, lane = tid & 63;
    const int z = blockIdx.z;
    const int r0w = blockIdx.x * 64 + wave * 16;
    const int m0 = blockIdx.y * 16;
    const unsigned short* Xh = z ? Xh_d : Xh_e;
    const unsigned short* Xl = z ? Xl_d : Xl_e;
    const unsigned short* Wh = z ? Wh_d : Wh_e;
    const unsigned short* Wl = z ? Wl_d : Wl_e;

    const int row = lane & 15;            // m-index for A, n-index for B
    const int quad = lane >> 4;
    const int kq = quad * 8;

    const unsigned short* pah = Xh + (long)(r0w + row) * 512 + kq;
    const unsigned short* pal = Xl + (long)(r0w + row) * 512 + kq;
    const unsigned short* pbh = Wh + (long)(m0 + row) * 512 + kq;
    const unsigned short* pbl = Wl + (long)(m0 + row) * 512 + kq;

    f32x4 acc0 = {0.f, 0.f, 0.f, 0.f};
    f32x4 acc1 = {0.f, 0.f, 0.f, 0.f};

    bf16x8 Ah = *(const bf16x8*)pah, Al = *(const bf16x8*)pal;
    bf16x8 Bh = *(const bf16x8*)pbh, Bl = *(const bf16x8*)pbl;
#pragma unroll
    for (int k0 = 32; k0 <= 512; k0 += 32) {
        bf16x8 Ah2 = Ah, Al2 = Al, Bh2 = Bh, Bl2 = Bl;
        if (k0 < 512) {
            Ah2 = *(const bf16x8*)(pah + k0);
            Al2 = *(const bf16x8*)(pal + k0);
            Bh2 = *(const bf16x8*)(pbh + k0);
            Bl2 = *(const bf16x8*)(pbl + k0);
        }
        acc0 = __builtin_amdgcn_mfma_f32_16x16x32_bf16(Ah, Bh, acc0, 0, 0, 0);
        acc1 = __builtin_amdgcn_mfma_f32_16x16x32_bf16(Ah, Bl, acc1, 0, 0, 0);
        acc1 = __builtin_amdgcn_mfma_f32_16x16x32_bf16(Al, Bh, acc1, 0, 0, 0);
        Ah = Ah2; Al = Al2; Bh = Bh2; Bl = Bl2;
    }

    if (z == 0) {
        // ET[b][m][e]: lane's 4 regs = 4 consecutive e -> one float4 store
        const int batch = r0w >> 8;
        const int e0 = (r0w & 255) + quad * 4;
        float4 v;
        v.x = fast_exp2((acc0[0] + acc1[0]) * TANH_SCALE);
        v.y = fast_exp2((acc0[1] + acc1[1]) * TANH_SCALE);
        v.z = fast_exp2((acc0[2] + acc1[2]) * TANH_SCALE);
        v.w = fast_exp2((acc0[3] + acc1[3]) * TANH_SCALE);
        *(float4*)&ET[(long)batch * HDIM * ENC + (long)(m0 + row) * ENC + e0] = v;
    } else {
        const float bq = bmlp[m0 + row];
        const int r = r0w + quad * 4;
#pragma unroll
        for (int i = 0; i < 4; ++i)
            Dmat[(long)(r + i) * HDIM + m0 + row] =
                fast_exp2((acc0[i] + acc1[i] + bq) * TANH_SCALE);
    }
}

// ---------------------------------------------------------------------------
// attn v3 (unchanged, passed R7): thread = e, 2 d-rows/block, 512 blocks.
// D0/D1/wo staged in LDS (ds_read_b128 broadcast); E^T coalesced, 16-deep
// register prefetch. logit = -2 * sum_m wo*rcp(fma(E,D,1)).
// ---------------------------------------------------------------------------
__global__ __launch_bounds__(256) void attn_kernel(
    const float* __restrict__ Dmat, const float* __restrict__ ET,
    const float* __restrict__ wo,
    const float* __restrict__ enc, const unsigned char* __restrict__ extm,
    float* __restrict__ attn_out)
{
    __shared__ __align__(16) float d0s[HDIM];
    __shared__ __align__(16) float d1s[HDIM];
    __shared__ __align__(16) float wos[HDIM];
    __shared__ float red[2][4][2];

    const int tid = threadIdx.x, lane = tid & 63, wave = tid >> 6;
    const int b = blockIdx.y, d0 = blockIdx.x * 2;

    const float* D0 = Dmat + ((long)b * DEC + d0) * HDIM;
    const float* ecol = ET + (long)b * HDIM * ENC + tid;

    *(float2*)&d0s[tid * 2] = *(const float2*)&D0[tid * 2];
    *(float2*)&d1s[tid * 2] = *(const float2*)&D0[HDIM + tid * 2];
    *(float2*)&wos[tid * 2] = *(const float2*)&wo[tid * 2];

    float ev[16], nv[16];
#pragma unroll
    for (int j = 0; j < 16; ++j) ev[j] = ecol[j * ENC];
    __syncthreads();

    float acc0 = 0.f, acc1 = 0.f;
    for (int m = 0; m < HDIM; m += 16) {
        if (m + 16 < HDIM) {
#pragma unroll
            for (int j = 0; j < 16; ++j) nv[j] = ecol[(m + 16 + j) * ENC];
        }
        float4 dv0[4], dv1[4], wv[4];
#pragma unroll
        for (int q = 0; q < 4; ++q) {
            dv0[q] = *(const float4*)&d0s[m + q * 4];
            dv1[q] = *(const float4*)&d1s[m + q * 4];
            wv[q]  = *(const float4*)&wos[m + q * 4];
        }
#pragma unroll
        for (int j = 0; j < 16; ++j) {
            float w  = ((const float*)&wv[j >> 2])[j & 3];
            float t0 = fmaf(ev[j], ((const float*)&dv0[j >> 2])[j & 3], 1.0f);
            float t1 = fmaf(ev[j], ((const float*)&dv1[j >> 2])[j & 3], 1.0f);
            acc0 = fmaf(w, fast_rcp(t0), acc0);
            acc1 = fmaf(w, fast_rcp(t1), acc1);
        }
#pragma unroll
        for (int j = 0; j < 16; ++j) ev[j] = nv[j];
    }

    const int e = tid;
    const bool pad = (enc[((long)b * ENC + e) * HDIM] == 0.0f);
    const bool x0m = extm[((long)(b * DEC) + d0) * ENC + e] != 0;
    const bool x1m = extm[((long)(b * DEC) + d0 + 1) * ENC + e] != 0;
    float l0 = (pad || x0m) ? -__builtin_inff() : -2.0f * acc0;
    float l1 = (pad || x1m) ? -__builtin_inff() : -2.0f * acc1;

    float m0 = l0, m1 = l1;
#pragma unroll
    for (int off = 32; off >= 1; off >>= 1) {
        m0 = fmaxf(m0, __shfl_xor(m0, off, 64));
        m1 = fmaxf(m1, __shfl_xor(m1, off, 64));
    }
    if (lane == 0) { red[0][wave][0] = m0; red[0][wave][1] = m1; }
    __syncthreads();
    const float gm0 = fmaxf(fmaxf(red[0][0][0], red[0][1][0]), fmaxf(red[0][2][0], red[0][3][0]));
    const float gm1 = fmaxf(fmaxf(red[0][0][1], red[0][1][1]), fmaxf(red[0][2][1], red[0][3][1]));
    float p0 = fast_exp2((l0 - gm0) * LOG2E);
    float p1 = fast_exp2((l1 - gm1) * LOG2E);
    float s0 = p0, s1 = p1;
#pragma unroll
    for (int off = 32; off >= 1; off >>= 1) {
        s0 += __shfl_xor(s0, off, 64);
        s1 += __shfl_xor(s1, off, 64);
    }
    if (lane == 0) { red[1][wave][0] = s0; red[1][wave][1] = s1; }
    __syncthreads();
    const float gs0 = red[1][0][0] + red[1][1][0] + red[1][2][0] + red[1][3][0];
    const float gs1 = red[1][0][1] + red[1][1][1] + red[1][2][1] + red[1][3][1];
    attn_out[((long)(b * DEC) + d0) * ENC + e] = p0 * fast_rcp(gs0);
    attn_out[((long)(b * DEC) + d0 + 1) * ENC + e] = p1 * fast_rcp(gs1);
}

// ---------------------------------------------------------------------------
// ctx v3 (unchanged, passed R7): 8 d-rows x 256-h stripe per block.
// ---------------------------------------------------------------------------
#define C5_LOADW(WB, KOFF)                                                  \
    _Pragma("unroll")                                                       \
    for (int kk = 0; kk < 8; ++kk)                                          \
        WB[kk] = *(const float4*)&We[(long)((KOFF) + kk) * HDIM];

#define C5_FMA(WB, KOFF)                                                    \
    _Pragma("unroll")                                                       \
    for (int q = 0; q < 2; ++q) {                                           \
        float4 xq0 = *(const float4*)&as8[r0l][(KOFF) + q * 4];             \
        float4 xq1 = *(const float4*)&as8[r0l + 1][(KOFF) + q * 4];         \
        _Pragma("unroll")                                                   \
        for (int kk = 0; kk < 4; ++kk) {                                    \
            float4 w = WB[q * 4 + kk];                                      \
            float xv0 = ((const float*)&xq0)[kk];                           \
            float xv1 = ((const float*)&xq1)[kk];                           \
            acc[0][0] = fmaf(xv0, w.x, acc[0][0]);                          \
            acc[0][1] = fmaf(xv0, w.y, acc[0][1]);                          \
            acc[0][2] = fmaf(xv0, w.z, acc[0][2]);                          \
            acc[0][3] = fmaf(xv0, w.w, acc[0][3]);                          \
            acc[1][0] = fmaf(xv1, w.x, acc[1][0]);                          \
            acc[1][1] = fmaf(xv1, w.y, acc[1][1]);                          \
            acc[1][2] = fmaf(xv1, w.z, acc[1][2]);                          \
            acc[1][3] = fmaf(xv1, w.w, acc[1][3]);                          \
        }                                                                   \
    }

__global__ __launch_bounds__(256) void context_kernel(
    const float* __restrict__ attn, const float* __restrict__ enc,
    float* __restrict__ ctx)
{
    __shared__ __align__(16) float as8[8][ENC];
    const int tid = threadIdx.x;
    const int tx = tid & 63, ty = tid >> 6;
    const int r0 = blockIdx.x * 8;
    const int b = r0 >> 8;
    const int h0 = blockIdx.y * 256 + tx * 4;
    const int r0l = ty * 2;
    const float* We = enc + (long)b * ENC * HDIM + h0;

    {
        const float* ag = attn + (long)r0 * ENC;
#pragma unroll
        for (int i = 0; i < 2; ++i) {
            int idx = (tid + i * 256) * 4;
            *(float4*)&as8[0][idx] = *(const float4*)&ag[idx];
        }
    }

    float acc[2][4] = {};
    float4 Wa[8], Wb[8];
    C5_LOADW(Wa, 0)
    __syncthreads();

    for (int k0 = 0; k0 < ENC; k0 += 16) {
        C5_LOADW(Wb, k0 + 8)
        C5_FMA(Wa, k0)
        if (k0 + 16 < ENC) { C5_LOADW(Wa, k0 + 16) }
        C5_FMA(Wb, k0 + 8)
    }

#pragma unroll
    for (int i = 0; i < 2; ++i)
        *(float4*)&ctx[(long)(r0 + r0l + i) * HDIM + h0] =
            make_float4(acc[i][0], acc[i][1], acc[i][2], acc[i][3]);
}

// ---------------------------------------------------------------------------
extern "C" void kernel_launch(void* const* d_in, const int* in_sizes, int n_in,
                              void* d_out, int out_size, void* d_ws, size_t ws_size,
                              hipStream_t stream) {
    const float* dec = (const float*)d_in[0];
    const float* enc = (const float*)d_in[1];
    const unsigned char* extm = (const unsigned char*)d_in[2];
    const float* Wmlp = (const float*)d_in[3];
    const float* bmlp = (const float*)d_in[4];
    const float* Wout = (const float*)d_in[5];
    // d_in[6] = b_out: additive constant, cancels in softmax

    float* ctx = (float*)d_out;                    // [B, DEC, H]
    float* attn = ctx + (size_t)B * DEC * HDIM;    // [B, DEC, ENC]

    const size_t F = (size_t)B * DEC * HDIM;       // 524288
    float* ET = (float*)d_ws;                      // [B][H][ENC] fp32
    float* Dmat = ET + F;                          // [B*DEC][H] fp32
    unsigned short* Xh_e = (unsigned short*)(Dmat + F);
    unsigned short* Xl_e = Xh_e + F;
    unsigned short* Xh_d = Xl_e + F;
    unsigned short* Xl_d = Xh_d + F;
    unsigned short* Wh_e = Xl_d + F;               // [512 m][512 k] bf16
    unsigned short* Wl_e = Wh_e + HDIM * HDIM;
    unsigned short* Wh_d = Wl_e + HDIM * HDIM;
    unsigned short* Wl_d = Wh_d + HDIM * HDIM;

    convert_kernel<<<dim3(256, 1, 4), 256, 0, stream>>>(
        enc, dec, Wmlp, Xh_e, Xl_e, Xh_d, Xl_d, Wh_e, Wl_e, Wh_d, Wl_d);
    proj_mfma_kernel<<<dim3(16, 32, 2), 256, 0, stream>>>(
        Xh_e, Xl_e, Xh_d, Xl_d, Wh_e, Wl_e, Wh_d, Wl_d, bmlp, ET, Dmat);
    attn_kernel<<<dim3(DEC / 2, B), 256, 0, stream>>>(Dmat, ET, Wout, enc, extm, attn);
    context_kernel<<<dim3(128, 2), 256, 0, stream>>>(attn, enc, ctx);
}

// Round 9
// 137.707 us; speedup vs baseline: 1.1236x; 1.0064x over previous
//
#include <hip/hip_runtime.h>
#include <math.h>

#define B 4
#define DEC 256
#define ENC 256
#define HDIM 512

// exp2(x*TANH_SCALE) == e^{2x};  tanh(x) = 1 - 2/(1+e^{2x})
#define TANH_SCALE 2.8853900817779268f
#define LOG2E 1.4426950408889634f

__device__ __forceinline__ float fast_exp2(float x) { return __builtin_amdgcn_exp2f(x); }
__device__ __forceinline__ float fast_rcp(float x)  { return __builtin_amdgcn_rcpf(x); }

typedef __attribute__((ext_vector_type(8))) short bf16x8;   // 8 bf16 = 4 VGPR
typedef __attribute__((ext_vector_type(4))) short bf16x4;
typedef __attribute__((ext_vector_type(4))) float f32x4;

__device__ __forceinline__ unsigned short bf16_rne(float x) {
    unsigned u = __float_as_uint(x);
    return (unsigned short)((u + 0x7FFFu + ((u >> 16) & 1u)) >> 16);
}
__device__ __forceinline__ float bf16_to_f(unsigned short h) {
    return __uint_as_float((unsigned)h << 16);
}

// ---------------------------------------------------------------------------
// convert: fp32 -> bf16 hi/lo split (unchanged from R8).
//  z=0/1: X (enc/dec) [1024][512] -> Xh/Xl same layout. 8 els/thread.
//  z=2/3: W half (enc/dec) [512k][512m] -> WhT/WlT TRANSPOSED [512m][512k].
// ---------------------------------------------------------------------------
__global__ __launch_bounds__(256) void convert_kernel(
    const float* __restrict__ enc, const float* __restrict__ dec,
    const float* __restrict__ Wmlp,
    unsigned short* __restrict__ Xh_e, unsigned short* __restrict__ Xl_e,
    unsigned short* __restrict__ Xh_d, unsigned short* __restrict__ Xl_d,
    unsigned short* __restrict__ Wh_e, unsigned short* __restrict__ Wl_e,
    unsigned short* __restrict__ Wh_d, unsigned short* __restrict__ Wl_d)
{
    const int tid = threadIdx.x, z = blockIdx.z;
    if (z < 2) {
        const float* X = z ? dec : enc;
        unsigned short* H = z ? Xh_d : Xh_e;
        unsigned short* L = z ? Xl_d : Xl_e;
        const long i8 = ((long)blockIdx.x * 256 + tid) * 8;
        float4 v0 = *(const float4*)(X + i8);
        float4 v1 = *(const float4*)(X + i8 + 4);
        float xs[8] = {v0.x, v0.y, v0.z, v0.w, v1.x, v1.y, v1.z, v1.w};
        bf16x8 hv, lv;
#pragma unroll
        for (int j = 0; j < 8; ++j) {
            unsigned short h = bf16_rne(xs[j]);
            hv[j] = (short)h;
            lv[j] = (short)bf16_rne(xs[j] - bf16_to_f(h));
        }
        *(bf16x8*)(H + i8) = hv;
        *(bf16x8*)(L + i8) = lv;
    } else {
        const float* Wsrc = Wmlp + (z == 3 ? (long)HDIM * HDIM : 0);
        unsigned short* H = (z == 3) ? Wh_d : Wh_e;
        unsigned short* L = (z == 3) ? Wl_d : Wl_e;
        const int t = blockIdx.x * 256 + tid;
        const int m = t & 511;
        const int k0 = (t >> 9) << 2;
        bf16x4 hv, lv;
#pragma unroll
        for (int j = 0; j < 4; ++j) {
            float x = Wsrc[(long)(k0 + j) * 512 + m];
            unsigned short h = bf16_rne(x);
            hv[j] = (short)h;
            lv[j] = (short)bf16_rne(x - bf16_to_f(h));
        }
        *(bf16x4*)(H + (long)m * 512 + k0) = hv;
        *(bf16x4*)(L + (long)m * 512 + k0) = lv;
    }
}

// ---------------------------------------------------------------------------
// proj via MFMA (unchanged from R8): bf16 hi/lo, 3 mfma/K-step.
// grid (16, 32, 2) = 1024 blocks; wave = one 16x16 C-tile.
// ---------------------------------------------------------------------------
__global__ __launch_bounds__(256) void proj_mfma_kernel(
    const unsigned short* __restrict__ Xh_e, const unsigned short* __restrict__ Xl_e,
    const unsigned short* __restrict__ Xh_d, const unsigned short* __restrict__ Xl_d,
    const unsigned short* __restrict__ Wh_e, const unsigned short* __restrict__ Wl_e,
    const unsigned short* __restrict__ Wh_d, const unsigned short* __restrict__ Wl_d,
    const float* __restrict__ bmlp,
    float* __restrict__ ET, float* __restrict__ Dmat)
{
    const int tid = threadIdx.x;
    const int wave = tid >> 6, lane = tid & 63;
    const int z = blockIdx.z;
    const int r0w = blockIdx.x * 64 + wave * 16;
    const int m0 = blockIdx.y * 16;
    const unsigned short* Xh = z ? Xh_d : Xh_e;
    const unsigned short* Xl = z ? Xl_d : Xl_e;
    const unsigned short* Wh = z ? Wh_d : Wh_e;
    const unsigned short* Wl = z ? Wl_d : Wl_e;

    const int row = lane & 15;
    const int quad = lane >> 4;
    const int kq = quad * 8;

    const unsigned short* pah = Xh + (long)(r0w + row) * 512 + kq;
    const unsigned short* pal = Xl + (long)(r0w + row) * 512 + kq;
    const unsigned short* pbh = Wh + (long)(m0 + row) * 512 + kq;
    const unsigned short* pbl = Wl + (long)(m0 + row) * 512 + kq;

    f32x4 acc0 = {0.f, 0.f, 0.f, 0.f};
    f32x4 acc1 = {0.f, 0.f, 0.f, 0.f};

    bf16x8 Ah = *(const bf16x8*)pah, Al = *(const bf16x8*)pal;
    bf16x8 Bh = *(const bf16x8*)pbh, Bl = *(const bf16x8*)pbl;
#pragma unroll
    for (int k0 = 32; k0 <= 512; k0 += 32) {
        bf16x8 Ah2 = Ah, Al2 = Al, Bh2 = Bh, Bl2 = Bl;
        if (k0 < 512) {
            Ah2 = *(const bf16x8*)(pah + k0);
            Al2 = *(const bf16x8*)(pal + k0);
            Bh2 = *(const bf16x8*)(pbh + k0);
            Bl2 = *(const bf16x8*)(pbl + k0);
        }
        acc0 = __builtin_amdgcn_mfma_f32_16x16x32_bf16(Ah, Bh, acc0, 0, 0, 0);
        acc1 = __builtin_amdgcn_mfma_f32_16x16x32_bf16(Ah, Bl, acc1, 0, 0, 0);
        acc1 = __builtin_amdgcn_mfma_f32_16x16x32_bf16(Al, Bh, acc1, 0, 0, 0);
        Ah = Ah2; Al = Al2; Bh = Bh2; Bl = Bl2;
    }

    if (z == 0) {
        const int batch = r0w >> 8;
        const int e0 = (r0w & 255) + quad * 4;
        float4 v;
        v.x = fast_exp2((acc0[0] + acc1[0]) * TANH_SCALE);
        v.y = fast_exp2((acc0[1] + acc1[1]) * TANH_SCALE);
        v.z = fast_exp2((acc0[2] + acc1[2]) * TANH_SCALE);
        v.w = fast_exp2((acc0[3] + acc1[3]) * TANH_SCALE);
        *(float4*)&ET[(long)batch * HDIM * ENC + (long)(m0 + row) * ENC + e0] = v;
    } else {
        const float bq = bmlp[m0 + row];
        const int r = r0w + quad * 4;
#pragma unroll
        for (int i = 0; i < 4; ++i)
            Dmat[(long)(r + i) * HDIM + m0 + row] =
                fast_exp2((acc0[i] + acc1[i] + bq) * TANH_SCALE);
    }
}

// ---------------------------------------------------------------------------
// attn_partial: grid (64, 4, B) = 1024 blocks (4/CU, 16 waves/CU).
// Block: 4 d-rows x 256 e (thread=e) x 128 m (m-quarter = blockIdx.y).
// D rows + wo staged in LDS (broadcast b128 reads, conflict-free).
// part[q][(b*DEC+d)*ENC + e] = sum_{m in quarter} wo[m]*rcp(fma(E,D,1))
// ---------------------------------------------------------------------------
__global__ __launch_bounds__(256) void attn_partial_kernel(
    const float* __restrict__ Dmat, const float* __restrict__ ET,
    const float* __restrict__ wo, float* __restrict__ part)
{
    __shared__ __align__(16) float ds[4][128];
    __shared__ __align__(16) float wos[128];

    const int tid = threadIdx.x;
    const int b = blockIdx.z, d0 = blockIdx.x * 4, mq = blockIdx.y;
    const int m0q = mq * 128;

    const float* Drow = Dmat + ((long)b * DEC + d0) * HDIM + m0q;
    if (tid < 128) {
#pragma unroll
        for (int r = 0; r < 4; ++r)
            ds[r][tid] = Drow[(long)r * HDIM + tid];
        wos[tid] = wo[m0q + tid];
    }

    const float* ecol = ET + (long)b * HDIM * ENC + (long)m0q * ENC + tid;

    float ev[16], nv[16];
#pragma unroll
    for (int j = 0; j < 16; ++j) ev[j] = ecol[j * ENC];
    __syncthreads();

    float acc[4] = {0.f, 0.f, 0.f, 0.f};
    for (int m = 0; m < 128; m += 16) {
        if (m + 16 < 128) {
#pragma unroll
            for (int j = 0; j < 16; ++j) nv[j] = ecol[(m + 16 + j) * ENC];
        }
        float4 dv[4][4], wv[4];
#pragma unroll
        for (int q = 0; q < 4; ++q) {
#pragma unroll
            for (int r = 0; r < 4; ++r)
                dv[r][q] = *(const float4*)&ds[r][m + q * 4];
            wv[q] = *(const float4*)&wos[m + q * 4];
        }
#pragma unroll
        for (int j = 0; j < 16; ++j) {
            float w = ((const float*)&wv[j >> 2])[j & 3];
#pragma unroll
            for (int r = 0; r < 4; ++r) {
                float t = fmaf(ev[j], ((const float*)&dv[r][j >> 2])[j & 3], 1.0f);
                acc[r] = fmaf(w, fast_rcp(t), acc[r]);
            }
        }
#pragma unroll
        for (int j = 0; j < 16; ++j) ev[j] = nv[j];
    }

    float* pq = part + (long)mq * (B * DEC * ENC);
#pragma unroll
    for (int r = 0; r < 4; ++r)
        pq[((long)b * DEC + d0 + r) * ENC + tid] = acc[r];
}

// ---------------------------------------------------------------------------
// attn_finish: 512 blocks (2 d-rows, thread=e). Sum 4 partials, masks,
// softmax over e, write attn.
// ---------------------------------------------------------------------------
__global__ __launch_bounds__(256) void attn_finish_kernel(
    const float* __restrict__ part,
    const float* __restrict__ enc, const unsigned char* __restrict__ extm,
    float* __restrict__ attn_out)
{
    __shared__ float red[2][4][2];
    const int tid = threadIdx.x, lane = tid & 63, wave = tid >> 6;
    const int b = blockIdx.y, d0 = blockIdx.x * 2;
    const long g0 = (long)b * DEC + d0;
    const long NQ = (long)B * DEC * ENC;

    float a0 = 0.f, a1 = 0.f;
#pragma unroll
    for (int q = 0; q < 4; ++q) {
        a0 += part[q * NQ + g0 * ENC + tid];
        a1 += part[q * NQ + (g0 + 1) * ENC + tid];
    }

    const int e = tid;
    const bool pad = (enc[((long)b * ENC + e) * HDIM] == 0.0f);
    const bool x0m = extm[g0 * ENC + e] != 0;
    const bool x1m = extm[(g0 + 1) * ENC + e] != 0;
    float l0 = (pad || x0m) ? -__builtin_inff() : -2.0f * a0;
    float l1 = (pad || x1m) ? -__builtin_inff() : -2.0f * a1;

    float m0 = l0, m1 = l1;
#pragma unroll
    for (int off = 32; off >= 1; off >>= 1) {
        m0 = fmaxf(m0, __shfl_xor(m0, off, 64));
        m1 = fmaxf(m1, __shfl_xor(m1, off, 64));
    }
    if (lane == 0) { red[0][wave][0] = m0; red[0][wave][1] = m1; }
    __syncthreads();
    const float gm0 = fmaxf(fmaxf(red[0][0][0], red[0][1][0]), fmaxf(red[0][2][0], red[0][3][0]));
    const float gm1 = fmaxf(fmaxf(red[0][0][1], red[0][1][1]), fmaxf(red[0][2][1], red[0][3][1]));
    float p0 = fast_exp2((l0 - gm0) * LOG2E);
    float p1 = fast_exp2((l1 - gm1) * LOG2E);
    float s0 = p0, s1 = p1;
#pragma unroll
    for (int off = 32; off >= 1; off >>= 1) {
        s0 += __shfl_xor(s0, off, 64);
        s1 += __shfl_xor(s1, off, 64);
    }
    if (lane == 0) { red[1][wave][0] = s0; red[1][wave][1] = s1; }
    __syncthreads();
    const float gs0 = red[1][0][0] + red[1][1][0] + red[1][2][0] + red[1][3][0];
    const float gs1 = red[1][0][1] + red[1][1][1] + red[1][2][1] + red[1][3][1];
    attn_out[g0 * ENC + e] = p0 * fast_rcp(gs0);
    attn_out[(g0 + 1) * ENC + e] = p1 * fast_rcp(gs1);
}

// ---------------------------------------------------------------------------
// ctx v3 (unchanged, passing): 8 d-rows x 256-h stripe per block.
// ---------------------------------------------------------------------------
#define C5_LOADW(WB, KOFF)                                                  \
    _Pragma("unroll")                                                       \
    for (int kk = 0; kk < 8; ++kk)                                          \
        WB[kk] = *(const float4*)&We[(long)((KOFF) + kk) * HDIM];

#define C5_FMA(WB, KOFF)                                                    \
    _Pragma("unroll")                                                       \
    for (int q = 0; q < 2; ++q) {                                           \
        float4 xq0 = *(const float4*)&as8[r0l][(KOFF) + q * 4];             \
        float4 xq1 = *(const float4*)&as8[r0l + 1][(KOFF) + q * 4];         \
        _Pragma("unroll")                                                   \
        for (int kk = 0; kk < 4; ++kk) {                                    \
            float4 w = WB[q * 4 + kk];                                      \
            float xv0 = ((const float*)&xq0)[kk];                           \
            float xv1 = ((const float*)&xq1)[kk];                           \
            acc[0][0] = fmaf(xv0, w.x, acc[0][0]);                          \
            acc[0][1] = fmaf(xv0, w.y, acc[0][1]);                          \
            acc[0][2] = fmaf(xv0, w.z, acc[0][2]);                          \
            acc[0][3] = fmaf(xv0, w.w, acc[0][3]);                          \
            acc[1][0] = fmaf(xv1, w.x, acc[1][0]);                          \
            acc[1][1] = fmaf(xv1, w.y, acc[1][1]);                          \
            acc[1][2] = fmaf(xv1, w.z, acc[1][2]);                          \
            acc[1][3] = fmaf(xv1, w.w, acc[1][3]);                          \
        }                                                                   \
    }

__global__ __launch_bounds__(256) void context_kernel(
    const float* __restrict__ attn, const float* __restrict__ enc,
    float* __restrict__ ctx)
{
    __shared__ __align__(16) float as8[8][ENC];
    const int tid = threadIdx.x;
    const int tx = tid & 63, ty = tid >> 6;
    const int r0 = blockIdx.x * 8;
    const int b = r0 >> 8;
    const int h0 = blockIdx.y * 256 + tx * 4;
    const int r0l = ty * 2;
    const float* We = enc + (long)b * ENC * HDIM + h0;

    {
        const float* ag = attn + (long)r0 * ENC;
#pragma unroll
        for (int i = 0; i < 2; ++i) {
            int idx = (tid + i * 256) * 4;
            *(float4*)&as8[0][idx] = *(const float4*)&ag[idx];
        }
    }

    float acc[2][4] = {};
    float4 Wa[8], Wb[8];
    C5_LOADW(Wa, 0)
    __syncthreads();

    for (int k0 = 0; k0 < ENC; k0 += 16) {
        C5_LOADW(Wb, k0 + 8)
        C5_FMA(Wa, k0)
        if (k0 + 16 < ENC) { C5_LOADW(Wa, k0 + 16) }
        C5_FMA(Wb, k0 + 8)
    }

#pragma unroll
    for (int i = 0; i < 2; ++i)
        *(float4*)&ctx[(long)(r0 + r0l + i) * HDIM + h0] =
            make_float4(acc[i][0], acc[i][1], acc[i][2], acc[i][3]);
}

// ---------------------------------------------------------------------------
extern "C" void kernel_launch(void* const* d_in, const int* in_sizes, int n_in,
                              void* d_out, int out_size, void* d_ws, size_t ws_size,
                              hipStream_t stream) {
    const float* dec = (const float*)d_in[0];
    const float* enc = (const float*)d_in[1];
    const unsigned char* extm = (const unsigned char*)d_in[2];
    const float* Wmlp = (const float*)d_in[3];
    const float* bmlp = (const float*)d_in[4];
    const float* Wout = (const float*)d_in[5];
    // d_in[6] = b_out: additive constant, cancels in softmax

    float* ctx = (float*)d_out;                    // [B, DEC, H]
    float* attn = ctx + (size_t)B * DEC * HDIM;    // [B, DEC, ENC]

    const size_t F = (size_t)B * DEC * HDIM;       // 524288
    float* ET = (float*)d_ws;                      // [B][H][ENC] fp32
    float* Dmat = ET + F;                          // [B*DEC][H] fp32
    unsigned short* Xh_e = (unsigned short*)(Dmat + F);
    unsigned short* Xl_e = Xh_e + F;
    unsigned short* Xh_d = Xl_e + F;
    unsigned short* Xl_d = Xh_d + F;
    unsigned short* Wh_e = Xl_d + F;               // [512 m][512 k] bf16
    unsigned short* Wl_e = Wh_e + HDIM * HDIM;
    unsigned short* Wh_d = Wl_e + HDIM * HDIM;
    unsigned short* Wl_d = Wh_d + HDIM * HDIM;
    float* part = (float*)(Wl_d + HDIM * HDIM);    // [4][B*DEC][ENC] fp32

    convert_kernel<<<dim3(256, 1, 4), 256, 0, stream>>>(
        enc, dec, Wmlp, Xh_e, Xl_e, Xh_d, Xl_d, Wh_e, Wl_e, Wh_d, Wl_d);
    proj_mfma_kernel<<<dim3(16, 32, 2), 256, 0, stream>>>(
        Xh_e, Xl_e, Xh_d, Xl_d, Wh_e, Wl_e, Wh_d, Wl_d, bmlp, ET, Dmat);
    attn_partial_kernel<<<dim3(DEC / 4, 4, B), 256, 0, stream>>>(Dmat, ET, Wout, part);
    attn_finish_kernel<<<dim3(DEC / 2, B), 256, 0, stream>>>(part, enc, extm, attn);
    context_kernel<<<dim3(128, 2), 256, 0, stream>>>(attn, enc, ctx);
}

// Round 10
// 118.242 us; speedup vs baseline: 1.3086x; 1.1646x over previous
//
#include <hip/hip_runtime.h>
#include <math.h>

#define B 4
#define DEC 256
#define ENC 256
#define HDIM 512

// exp2(x*TANH_SCALE) == e^{2x};  tanh(x) = 1 - 2/(1+e^{2x})
#define TANH_SCALE 2.8853900817779268f
#define LOG2E 1.4426950408889634f

__device__ __forceinline__ float fast_exp2(float x) { return __builtin_amdgcn_exp2f(x); }
__device__ __forceinline__ float fast_rcp(float x)  { return __builtin_amdgcn_rcpf(x); }

typedef __attribute__((ext_vector_type(8))) short bf16x8;   // 8 bf16 = 4 VGPR
typedef __attribute__((ext_vector_type(4))) short bf16x4;
typedef __attribute__((ext_vector_type(4))) float f32x4;

__device__ __forceinline__ unsigned short bf16_rne(float x) {
    unsigned u = __float_as_uint(x);
    return (unsigned short)((u + 0x7FFFu + ((u >> 16) & 1u)) >> 16);
}
__device__ __forceinline__ float bf16_to_f(unsigned short h) {
    return __uint_as_float((unsigned)h << 16);
}

// Blocked-transpose W layout (shorts): ofs(m,k) = (m/16)*8192 + (k/8)*128 + (m%16)*8 + k%8
// -> proj B-frag wave-load = 512 B contiguous; convert writes = 128 B segments.
#define W_OFS(m, k) ((((long)(m) >> 4) << 13) + (((long)(k) >> 3) << 7) + (((m) & 15) << 3) + ((k) & 7))

// ---------------------------------------------------------------------------
// convert: fp32 -> bf16 hi/lo split.
//  z=0/1: X (enc/dec) -> Xh/Xl row-major (coalesced in+out). 8 els/thread.
//  z=2/3: W half -> blocked-transpose layout (coalesced reads, 128B-segment
//         writes instead of R8's 8B/1KB-stride scatter). 4 els/thread.
// grid (256, 1, 4) x 256 thr.
// ---------------------------------------------------------------------------
__global__ __launch_bounds__(256) void convert_kernel(
    const float* __restrict__ enc, const float* __restrict__ dec,
    const float* __restrict__ Wmlp,
    unsigned short* __restrict__ Xh_e, unsigned short* __restrict__ Xl_e,
    unsigned short* __restrict__ Xh_d, unsigned short* __restrict__ Xl_d,
    unsigned short* __restrict__ Wh_e, unsigned short* __restrict__ Wl_e,
    unsigned short* __restrict__ Wh_d, unsigned short* __restrict__ Wl_d)
{
    const int tid = threadIdx.x, z = blockIdx.z;
    if (z < 2) {
        const float* X = z ? dec : enc;
        unsigned short* H = z ? Xh_d : Xh_e;
        unsigned short* L = z ? Xl_d : Xl_e;
        const long i8 = ((long)blockIdx.x * 256 + tid) * 8;
        float4 v0 = *(const float4*)(X + i8);
        float4 v1 = *(const float4*)(X + i8 + 4);
        float xs[8] = {v0.x, v0.y, v0.z, v0.w, v1.x, v1.y, v1.z, v1.w};
        bf16x8 hv, lv;
#pragma unroll
        for (int j = 0; j < 8; ++j) {
            unsigned short h = bf16_rne(xs[j]);
            hv[j] = (short)h;
            lv[j] = (short)bf16_rne(xs[j] - bf16_to_f(h));
        }
        *(bf16x8*)(H + i8) = hv;
        *(bf16x8*)(L + i8) = lv;
    } else {
        const float* Wsrc = Wmlp + (z == 3 ? (long)HDIM * HDIM : 0);
        unsigned short* H = (z == 3) ? Wh_d : Wh_e;
        unsigned short* L = (z == 3) ? Wl_d : Wl_e;
        const int t = blockIdx.x * 256 + tid;     // 0..65535
        const int m = t & 511;
        const int k0 = (t >> 9) << 2;             // multiple of 4
        bf16x4 hv, lv;
#pragma unroll
        for (int j = 0; j < 4; ++j) {
            float x = Wsrc[(long)(k0 + j) * 512 + m];   // coalesced reads
            unsigned short h = bf16_rne(x);
            hv[j] = (short)h;
            lv[j] = (short)bf16_rne(x - bf16_to_f(h));
        }
        const long ofs = W_OFS(m, k0);            // 4 consecutive shorts
        *(bf16x4*)(H + ofs) = hv;
        *(bf16x4*)(L + ofs) = lv;
    }
}

// ---------------------------------------------------------------------------
// proj via MFMA v2: wave = 16 r x 32 m (2 C-tiles), block = 64 r x 32 m.
// grid (16, 16, 2) = 512 blocks -> 2 blocks/CU, 8 waves/CU.
// KEY CHANGE vs R8: K-loop is NOT unrolled (depth-1 explicit ping-pong,
// <=12 loads in flight) -- R8's full unroll could hoist ~64 loads (VGPR
// blow-up / vmcnt saturation). 4 independent acc chains interleave the
// hi/lo 3-mfma scheme (hh + hl + lh).
// Frag layouts (mfma_f32_16x16x32_bf16), verified on HW in R8:
//   A[m=lane&15][k=(lane>>4)*8+j]; B[k=(lane>>4)*8+j][n=lane&15]
//   C/D: col=lane&15, row=(lane>>4)*4+reg
// ---------------------------------------------------------------------------
__global__ __launch_bounds__(256) void proj_mfma_kernel(
    const unsigned short* __restrict__ Xh_e, const unsigned short* __restrict__ Xl_e,
    const unsigned short* __restrict__ Xh_d, const unsigned short* __restrict__ Xl_d,
    const unsigned short* __restrict__ Wh_e, const unsigned short* __restrict__ Wl_e,
    const unsigned short* __restrict__ Wh_d, const unsigned short* __restrict__ Wl_d,
    const float* __restrict__ bmlp,
    float* __restrict__ ET, float* __restrict__ Dmat)
{
    const int tid = threadIdx.x;
    const int wave = tid >> 6, lane = tid & 63;
    const int z = blockIdx.z;
    const int r0w = blockIdx.x * 64 + wave * 16;
    const int m0 = blockIdx.y * 32;
    const unsigned short* Xh = z ? Xh_d : Xh_e;
    const unsigned short* Xl = z ? Xl_d : Xl_e;
    const unsigned short* Wh = z ? Wh_d : Wh_e;
    const unsigned short* Wl = z ? Wl_d : Wl_e;

    const int col = lane & 15;
    const int quad = lane >> 4;

    const unsigned short* pah = Xh + (long)(r0w + col) * 512 + quad * 8;
    const unsigned short* pal = Xl + (long)(r0w + col) * 512 + quad * 8;
    // B blocked layout: tile base + quad*128 + col*8; k0 advance = k0*16 shorts
    const long bofs = ((long)(m0 >> 4) << 13) + (quad << 7) + (col << 3);
    const unsigned short* pb0h = Wh + bofs;
    const unsigned short* pb0l = Wl + bofs;
    const unsigned short* pb1h = Wh + bofs + 8192;
    const unsigned short* pb1l = Wl + bofs + 8192;

    f32x4 a0h = {0.f,0.f,0.f,0.f}, a0x = {0.f,0.f,0.f,0.f};
    f32x4 a1h = {0.f,0.f,0.f,0.f}, a1x = {0.f,0.f,0.f,0.f};

    bf16x8 Ah = *(const bf16x8*)pah,  Al = *(const bf16x8*)pal;
    bf16x8 B0h = *(const bf16x8*)pb0h, B0l = *(const bf16x8*)pb0l;
    bf16x8 B1h = *(const bf16x8*)pb1h, B1l = *(const bf16x8*)pb1l;

#pragma unroll 1
    for (int k0 = 0; k0 < 512; k0 += 32) {
        bf16x8 nAh = Ah, nAl = Al, nB0h = B0h, nB0l = B0l, nB1h = B1h, nB1l = B1l;
        if (k0 + 32 < 512) {
            nAh = *(const bf16x8*)(pah + k0 + 32);
            nAl = *(const bf16x8*)(pal + k0 + 32);
            const long ko = (long)(k0 + 32) << 4;
            nB0h = *(const bf16x8*)(pb0h + ko);
            nB0l = *(const bf16x8*)(pb0l + ko);
            nB1h = *(const bf16x8*)(pb1h + ko);
            nB1l = *(const bf16x8*)(pb1l + ko);
        }
        a0h = __builtin_amdgcn_mfma_f32_16x16x32_bf16(Ah, B0h, a0h, 0, 0, 0);
        a1h = __builtin_amdgcn_mfma_f32_16x16x32_bf16(Ah, B1h, a1h, 0, 0, 0);
        a0x = __builtin_amdgcn_mfma_f32_16x16x32_bf16(Ah, B0l, a0x, 0, 0, 0);
        a1x = __builtin_amdgcn_mfma_f32_16x16x32_bf16(Ah, B1l, a1x, 0, 0, 0);
        a0x = __builtin_amdgcn_mfma_f32_16x16x32_bf16(Al, B0h, a0x, 0, 0, 0);
        a1x = __builtin_amdgcn_mfma_f32_16x16x32_bf16(Al, B1h, a1x, 0, 0, 0);
        Ah = nAh; Al = nAl; B0h = nB0h; B0l = nB0l; B1h = nB1h; B1l = nB1l;
    }

    if (z == 0) {
        const int batch = r0w >> 8;
        const int e0 = (r0w & 255) + quad * 4;
        float* base = ET + (long)batch * HDIM * ENC;
        float4 v;
        v.x = fast_exp2((a0h[0] + a0x[0]) * TANH_SCALE);
        v.y = fast_exp2((a0h[1] + a0x[1]) * TANH_SCALE);
        v.z = fast_exp2((a0h[2] + a0x[2]) * TANH_SCALE);
        v.w = fast_exp2((a0h[3] + a0x[3]) * TANH_SCALE);
        *(float4*)&base[(long)(m0 + col) * ENC + e0] = v;
        v.x = fast_exp2((a1h[0] + a1x[0]) * TANH_SCALE);
        v.y = fast_exp2((a1h[1] + a1x[1]) * TANH_SCALE);
        v.z = fast_exp2((a1h[2] + a1x[2]) * TANH_SCALE);
        v.w = fast_exp2((a1h[3] + a1x[3]) * TANH_SCALE);
        *(float4*)&base[(long)(m0 + 16 + col) * ENC + e0] = v;
    } else {
        const float bq0 = bmlp[m0 + col];
        const float bq1 = bmlp[m0 + 16 + col];
        const int r = r0w + quad * 4;
#pragma unroll
        for (int i = 0; i < 4; ++i) {
            Dmat[(long)(r + i) * HDIM + m0 + col] =
                fast_exp2((a0h[i] + a0x[i] + bq0) * TANH_SCALE);
            Dmat[(long)(r + i) * HDIM + m0 + 16 + col] =
                fast_exp2((a1h[i] + a1x[i] + bq1) * TANH_SCALE);
        }
    }
}

// ---------------------------------------------------------------------------
// attn_partial (unchanged, passing): grid (64, 4, B) = 1024 blocks.
// Block: 4 d-rows x 256 e (thread=e) x 128 m (m-quarter).
// part[q][(b*DEC+d)*ENC+e] = sum_{m in quarter} wo[m]*rcp(fma(E,D,1))
// ---------------------------------------------------------------------------
__global__ __launch_bounds__(256) void attn_partial_kernel(
    const float* __restrict__ Dmat, const float* __restrict__ ET,
    const float* __restrict__ wo, float* __restrict__ part)
{
    __shared__ __align__(16) float ds[4][128];
    __shared__ __align__(16) float wos[128];

    const int tid = threadIdx.x;
    const int b = blockIdx.z, d0 = blockIdx.x * 4, mq = blockIdx.y;
    const int m0q = mq * 128;

    const float* Drow = Dmat + ((long)b * DEC + d0) * HDIM + m0q;
    if (tid < 128) {
#pragma unroll
        for (int r = 0; r < 4; ++r)
            ds[r][tid] = Drow[(long)r * HDIM + tid];
        wos[tid] = wo[m0q + tid];
    }

    const float* ecol = ET + (long)b * HDIM * ENC + (long)m0q * ENC + tid;

    float ev[16], nv[16];
#pragma unroll
    for (int j = 0; j < 16; ++j) ev[j] = ecol[j * ENC];
    __syncthreads();

    float acc[4] = {0.f, 0.f, 0.f, 0.f};
    for (int m = 0; m < 128; m += 16) {
        if (m + 16 < 128) {
#pragma unroll
            for (int j = 0; j < 16; ++j) nv[j] = ecol[(m + 16 + j) * ENC];
        }
        float4 dv[4][4], wv[4];
#pragma unroll
        for (int q = 0; q < 4; ++q) {
#pragma unroll
            for (int r = 0; r < 4; ++r)
                dv[r][q] = *(const float4*)&ds[r][m + q * 4];
            wv[q] = *(const float4*)&wos[m + q * 4];
        }
#pragma unroll
        for (int j = 0; j < 16; ++j) {
            float w = ((const float*)&wv[j >> 2])[j & 3];
#pragma unroll
            for (int r = 0; r < 4; ++r) {
                float t = fmaf(ev[j], ((const float*)&dv[r][j >> 2])[j & 3], 1.0f);
                acc[r] = fmaf(w, fast_rcp(t), acc[r]);
            }
        }
#pragma unroll
        for (int j = 0; j < 16; ++j) ev[j] = nv[j];
    }

    float* pq = part + (long)mq * (B * DEC * ENC);
#pragma unroll
    for (int r = 0; r < 4; ++r)
        pq[((long)b * DEC + d0 + r) * ENC + tid] = acc[r];
}

// ---------------------------------------------------------------------------
// attn_finish (unchanged, passing): sum 4 partials, masks, softmax, write.
// ---------------------------------------------------------------------------
__global__ __launch_bounds__(256) void attn_finish_kernel(
    const float* __restrict__ part,
    const float* __restrict__ enc, const unsigned char* __restrict__ extm,
    float* __restrict__ attn_out)
{
    __shared__ float red[2][4][2];
    const int tid = threadIdx.x, lane = tid & 63, wave = tid >> 6;
    const int b = blockIdx.y, d0 = blockIdx.x * 2;
    const long g0 = (long)b * DEC + d0;
    const long NQ = (long)B * DEC * ENC;

    float a0 = 0.f, a1 = 0.f;
#pragma unroll
    for (int q = 0; q < 4; ++q) {
        a0 += part[q * NQ + g0 * ENC + tid];
        a1 += part[q * NQ + (g0 + 1) * ENC + tid];
    }

    const int e = tid;
    const bool pad = (enc[((long)b * ENC + e) * HDIM] == 0.0f);
    const bool x0m = extm[g0 * ENC + e] != 0;
    const bool x1m = extm[(g0 + 1) * ENC + e] != 0;
    float l0 = (pad || x0m) ? -__builtin_inff() : -2.0f * a0;
    float l1 = (pad || x1m) ? -__builtin_inff() : -2.0f * a1;

    float m0 = l0, m1 = l1;
#pragma unroll
    for (int off = 32; off >= 1; off >>= 1) {
        m0 = fmaxf(m0, __shfl_xor(m0, off, 64));
        m1 = fmaxf(m1, __shfl_xor(m1, off, 64));
    }
    if (lane == 0) { red[0][wave][0] = m0; red[0][wave][1] = m1; }
    __syncthreads();
    const float gm0 = fmaxf(fmaxf(red[0][0][0], red[0][1][0]), fmaxf(red[0][2][0], red[0][3][0]));
    const float gm1 = fmaxf(fmaxf(red[0][0][1], red[0][1][1]), fmaxf(red[0][2][1], red[0][3][1]));
    float p0 = fast_exp2((l0 - gm0) * LOG2E);
    float p1 = fast_exp2((l1 - gm1) * LOG2E);
    float s0 = p0, s1 = p1;
#pragma unroll
    for (int off = 32; off >= 1; off >>= 1) {
        s0 += __shfl_xor(s0, off, 64);
        s1 += __shfl_xor(s1, off, 64);
    }
    if (lane == 0) { red[1][wave][0] = s0; red[1][wave][1] = s1; }
    __syncthreads();
    const float gs0 = red[1][0][0] + red[1][1][0] + red[1][2][0] + red[1][3][0];
    const float gs1 = red[1][0][1] + red[1][1][1] + red[1][2][1] + red[1][3][1];
    attn_out[g0 * ENC + e] = p0 * fast_rcp(gs0);
    attn_out[(g0 + 1) * ENC + e] = p1 * fast_rcp(gs1);
}

// ---------------------------------------------------------------------------
// ctx v3 (unchanged, passing): 8 d-rows x 256-h stripe per block.
// ---------------------------------------------------------------------------
#define C5_LOADW(WB, KOFF)                                                  \
    _Pragma("unroll")                                                       \
    for (int kk = 0; kk < 8; ++kk)                                          \
        WB[kk] = *(const float4*)&We[(long)((KOFF) + kk) * HDIM];

#define C5_FMA(WB, KOFF)                                                    \
    _Pragma("unroll")                                                       \
    for (int q = 0; q < 2; ++q) {                                           \
        float4 xq0 = *(const float4*)&as8[r0l][(KOFF) + q * 4];             \
        float4 xq1 = *(const float4*)&as8[r0l + 1][(KOFF) + q * 4];         \
        _Pragma("unroll")                                                   \
        for (int kk = 0; kk < 4; ++kk) {                                    \
            float4 w = WB[q * 4 + kk];                                      \
            float xv0 = ((const float*)&xq0)[kk];                           \
            float xv1 = ((const float*)&xq1)[kk];                           \
            acc[0][0] = fmaf(xv0, w.x, acc[0][0]);                          \
            acc[0][1] = fmaf(xv0, w.y, acc[0][1]);                          \
            acc[0][2] = fmaf(xv0, w.z, acc[0][2]);                          \
            acc[0][3] = fmaf(xv0, w.w, acc[0][3]);                          \
            acc[1][0] = fmaf(xv1, w.x, acc[1][0]);                          \
            acc[1][1] = fmaf(xv1, w.y, acc[1][1]);                          \
            acc[1][2] = fmaf(xv1, w.z, acc[1][2]);                          \
            acc[1][3] = fmaf(xv1, w.w, acc[1][3]);                          \
        }                                                                   \
    }

__global__ __launch_bounds__(256) void context_kernel(
    const float* __restrict__ attn, const float* __restrict__ enc,
    float* __restrict__ ctx)
{
    __shared__ __align__(16) float as8[8][ENC];
    const int tid = threadIdx.x;
    const int tx = tid & 63, ty = tid >> 6;
    const int r0 = blockIdx.x * 8;
    const int b = r0 >> 8;
    const int h0 = blockIdx.y * 256 + tx * 4;
    const int r0l = ty * 2;
    const float* We = enc + (long)b * ENC * HDIM + h0;

    {
        const float* ag = attn + (long)r0 * ENC;
#pragma unroll
        for (int i = 0; i < 2; ++i) {
            int idx = (tid + i * 256) * 4;
            *(float4*)&as8[0][idx] = *(const float4*)&ag[idx];
        }
    }

    float acc[2][4] = {};
    float4 Wa[8], Wb[8];
    C5_LOADW(Wa, 0)
    __syncthreads();

    for (int k0 = 0; k0 < ENC; k0 += 16) {
        C5_LOADW(Wb, k0 + 8)
        C5_FMA(Wa, k0)
        if (k0 + 16 < ENC) { C5_LOADW(Wa, k0 + 16) }
        C5_FMA(Wb, k0 + 8)
    }

#pragma unroll
    for (int i = 0; i < 2; ++i)
        *(float4*)&ctx[(long)(r0 + r0l + i) * HDIM + h0] =
            make_float4(acc[i][0], acc[i][1], acc[i][2], acc[i][3]);
}

// ---------------------------------------------------------------------------
extern "C" void kernel_launch(void* const* d_in, const int* in_sizes, int n_in,
                              void* d_out, int out_size, void* d_ws, size_t ws_size,
                              hipStream_t stream) {
    const float* dec = (const float*)d_in[0];
    const float* enc = (const float*)d_in[1];
    const unsigned char* extm = (const unsigned char*)d_in[2];
    const float* Wmlp = (const float*)d_in[3];
    const float* bmlp = (const float*)d_in[4];
    const float* Wout = (const float*)d_in[5];
    // d_in[6] = b_out: additive constant, cancels in softmax

    float* ctx = (float*)d_out;                    // [B, DEC, H]
    float* attn = ctx + (size_t)B * DEC * HDIM;    // [B, DEC, ENC]

    const size_t F = (size_t)B * DEC * HDIM;       // 524288
    float* ET = (float*)d_ws;                      // [B][H][ENC] fp32
    float* Dmat = ET + F;                          // [B*DEC][H] fp32
    unsigned short* Xh_e = (unsigned short*)(Dmat + F);
    unsigned short* Xl_e = Xh_e + F;
    unsigned short* Xh_d = Xl_e + F;
    unsigned short* Xl_d = Xh_d + F;
    unsigned short* Wh_e = Xl_d + F;               // blocked-T layout, 512*512
    unsigned short* Wl_e = Wh_e + HDIM * HDIM;
    unsigned short* Wh_d = Wl_e + HDIM * HDIM;
    unsigned short* Wl_d = Wh_d + HDIM * HDIM;
    float* part = (float*)(Wl_d + HDIM * HDIM);    // [4][B*DEC][ENC] fp32

    convert_kernel<<<dim3(256, 1, 4), 256, 0, stream>>>(
        enc, dec, Wmlp, Xh_e, Xl_e, Xh_d, Xl_d, Wh_e, Wl_e, Wh_d, Wl_d);
    proj_mfma_kernel<<<dim3(16, 16, 2), 256, 0, stream>>>(
        Xh_e, Xl_e, Xh_d, Xl_d, Wh_e, Wl_e, Wh_d, Wl_d, bmlp, ET, Dmat);
    attn_partial_kernel<<<dim3(DEC / 4, 4, B), 256, 0, stream>>>(Dmat, ET, Wout, part);
    attn_finish_kernel<<<dim3(DEC / 2, B), 256, 0, stream>>>(part, enc, extm, attn);
    context_kernel<<<dim3(128, 2), 256, 0, stream>>>(attn, enc, ctx);
}